// Round 3
// baseline (308.021 us; speedup 1.0000x reference)
//
#include <hip/hip_runtime.h>
#include <stdint.h>
#include <stddef.h>

// ---------------------------------------------------------------------------
// MultiHeadAttentionBlock: B=4, C=2048, D=1024, H=8, K=64, V=128
//
//   q_{b,g}[r][k]  = Pq[b*2048 + g*256 + r/8][(r%8)*64 + k]   (contiguous [2048,64])
//   out[b, c, h, d] = sum_c2 att_{b,g=c/256}[r=(c%256)*8+h][c2] * v_{b,h}[c2][d]
//   att[r][c2] = exp(s[r][c2]/8) / sum_r' exp(s[r'][c2]/8)    (softmax over r)
//
// R3 redesign of pass2 (was LDS-BW-bound, 36 KB/wave/cc):
//  * S^T via mfma 16x16x32 (D: c2=quad*4+reg, r=lc) feeds PV directly as the
//    B-frag of mfma_f32_16x16x16bf16_1k (k=quad*4+j, n=lc) -> P never touches
//    LDS, no ps round-trip, no mid-cc barrier.
//  * pass1 stores -ln(colsum); P = exp(fma(s,0.125,lrd)) folds the softmax
//    denominator into the exp argument (1 FMA, no rden mult, no rd staging).
//  * q B-frags preloaded to registers (qs read once).
//  -> 24 KB LDS/wave/cc, 46 KB LDS/block.
// Also: 3 projection GEMMs fused into one launch (Wt rows 0-511=Mq^T,
// 512-1023=Mk^T, 1024-2047=Mv^T are contiguous in ws), 3 cvtT fused.
// ---------------------------------------------------------------------------

typedef short     bf8v  __attribute__((ext_vector_type(8)));   // 8 x bf16 (x32 A/B frag)
typedef short     bf4v  __attribute__((ext_vector_type(4)));   // 4 x bf16 (x16 A/B frag)
typedef float     f4v   __attribute__((ext_vector_type(4)));   // 4 x f32 (C/D frag)
typedef unsigned short u16x4 __attribute__((ext_vector_type(4)));
typedef unsigned short u16x8 __attribute__((ext_vector_type(8)));

__device__ __forceinline__ unsigned short f2bf(float f) {  // RNE f32->bf16
    union { float f; uint32_t u; } v; v.f = f;
    return (unsigned short)((v.u + 0x7fffu + ((v.u >> 16) & 1u)) >> 16);
}

#define MFMA32(A, B, C) __builtin_amdgcn_mfma_f32_16x16x32_bf16((A), (B), (C), 0, 0, 0)
#define MFMA16(A, B, C) __builtin_amdgcn_mfma_f32_16x16x16bf16_1k((A), (B), (C), 0, 0, 0)

// -------------------- fp32 -> bf16 elementwise convert ----------------------
__global__ __launch_bounds__(256) void k_cvt(const float* __restrict__ in,
                                             unsigned short* __restrict__ out, int n4) {
    int i = blockIdx.x * 256 + threadIdx.x;
    if (i >= n4) return;
    f4v v = *(const f4v*)(in + (size_t)i * 4);
    u16x4 o;
    o[0] = f2bf(v[0]); o[1] = f2bf(v[1]); o[2] = f2bf(v[2]); o[3] = f2bf(v[3]);
    *(u16x4*)(out + (size_t)i * 4) = o;
}

// ---- fp32 [1024][N] -> bf16 transposed [N][1024], all 3 weights fused ------
__global__ __launch_bounds__(256) void k_cvtT3(const float* __restrict__ Mq,
                                               const float* __restrict__ Mk,
                                               const float* __restrict__ Mv,
                                               unsigned short* __restrict__ wqt,
                                               unsigned short* __restrict__ wkt,
                                               unsigned short* __restrict__ wvt) {
    __shared__ unsigned short t[64][68];
    const int tid = threadIdx.x;
    const int tr = tid >> 4, tc4 = (tid & 15) * 4;
    const float* in; unsigned short* outT; int Ncols, cb;
    if (blockIdx.z == 0) {
        if (blockIdx.x < 8) { in = Mq; outT = wqt; Ncols = 512; cb = blockIdx.x * 64; }
        else                { in = Mk; outT = wkt; Ncols = 512; cb = (blockIdx.x - 8) * 64; }
    } else                  { in = Mv; outT = wvt; Ncols = 1024; cb = blockIdx.x * 64; }
    const int rb = blockIdx.y * 64;
#pragma unroll
    for (int p = 0; p < 4; ++p) {
        int r = tr + p * 16;
        f4v v = *(const f4v*)(in + (size_t)(rb + r) * Ncols + cb + tc4);
        t[r][tc4 + 0] = f2bf(v[0]); t[r][tc4 + 1] = f2bf(v[1]);
        t[r][tc4 + 2] = f2bf(v[2]); t[r][tc4 + 3] = f2bf(v[3]);
    }
    __syncthreads();
#pragma unroll
    for (int p = 0; p < 4; ++p) {
        int r = tr + p * 16;               // output row = input col cb + r
        u16x4 o;
        o[0] = t[tc4 + 0][r]; o[1] = t[tc4 + 1][r];
        o[2] = t[tc4 + 2][r]; o[3] = t[tc4 + 3][r];
        *(u16x4*)(outT + (size_t)(cb + r) * 1024 + rb + tc4) = o;
    }
}

// -------- bf16 transpose [2048][128] -> [128][2048], 32 batches (b,h) -------
__global__ __launch_bounds__(256) void k_T(const unsigned short* __restrict__ in,
                                           unsigned short* __restrict__ out) {
    __shared__ unsigned short t[64][68];
    const int tid = threadIdx.x;
    const int tr = tid >> 4, tc4 = (tid & 15) * 4;
    const int rb = blockIdx.y * 64, cb = blockIdx.x * 64;
    const unsigned short* ib = in  + (size_t)blockIdx.z * 262144;
    unsigned short*       ob = out + (size_t)blockIdx.z * 262144;
#pragma unroll
    for (int p = 0; p < 4; ++p) {
        int r = tr + p * 16;
        u16x4 v = *(const u16x4*)(ib + (size_t)(rb + r) * 128 + cb + tc4);
        t[r][tc4 + 0] = v[0]; t[r][tc4 + 1] = v[1];
        t[r][tc4 + 2] = v[2]; t[r][tc4 + 3] = v[3];
    }
    __syncthreads();
#pragma unroll
    for (int p = 0; p < 4; ++p) {
        int r = tr + p * 16;
        u16x4 o;
        o[0] = t[tc4 + 0][r]; o[1] = t[tc4 + 1][r];
        o[2] = t[tc4 + 2][r]; o[3] = t[tc4 + 3][r];
        *(u16x4*)(ob + (size_t)(cb + r) * 2048 + rb + tc4) = o;
    }
}

// ------- fused projection GEMM: {Pq,Pk,Pv} = Xb[8192][1024] @ {Mq,Mk,Mv} ----
// Wt = [2048][1024] (wqt|wkt|wvt stacked). Computed as C^T: 4 regs = 4 cols.
__global__ __launch_bounds__(256, 2) void k_gemm(const unsigned short* __restrict__ X,
                                                 const unsigned short* __restrict__ Wt,
                                                 unsigned short* __restrict__ pq,
                                                 unsigned short* __restrict__ pk,
                                                 unsigned short* __restrict__ pv) {
    __shared__ __align__(16) unsigned short xs[128][72];
    __shared__ __align__(16) unsigned short wls[128][72];
    const int tid = threadIdx.x;
    const int lane = tid & 63, w = tid >> 6;
    const int lc = lane & 15, quad = lane >> 4;
    const int rowb = blockIdx.x * 128, cb = blockIdx.y;

    unsigned short* outp; int N, colb;
    if (cb < 4)      { outp = pq; N = 512;  colb = cb * 128; }
    else if (cb < 8) { outp = pk; N = 512;  colb = (cb - 4) * 128; }
    else             { outp = pv; N = 1024; colb = (cb - 8) * 128; }

    f4v acc[2][8];
#pragma unroll
    for (int mt = 0; mt < 2; ++mt)
#pragma unroll
        for (int nt = 0; nt < 8; ++nt) acc[mt][nt] = f4v{0.f, 0.f, 0.f, 0.f};

    for (int k0 = 0; k0 < 1024; k0 += 64) {
#pragma unroll
        for (int p = 0; p < 4; ++p) {
            int v = tid + p * 256;
            int r = v >> 3, s = (v & 7) * 8;
            *(u16x8*)(&xs[r][s])  = *(const u16x8*)(X  + (size_t)(rowb + r) * 1024 + k0 + s);
            *(u16x8*)(&wls[r][s]) = *(const u16x8*)(Wt + (size_t)(cb * 128 + r) * 1024 + k0 + s);
        }
        __syncthreads();
#pragma unroll
        for (int ks = 0; ks < 2; ++ks) {
            int kk = ks * 32 + quad * 8;
            bf8v bx[8];
#pragma unroll
            for (int nt = 0; nt < 8; ++nt) bx[nt] = *(const bf8v*)(&xs[nt * 16 + lc][kk]);
#pragma unroll
            for (int mt = 0; mt < 2; ++mt) {
                bf8v a = *(const bf8v*)(&wls[w * 32 + mt * 16 + lc][kk]);
#pragma unroll
                for (int nt = 0; nt < 8; ++nt) acc[mt][nt] = MFMA32(a, bx[nt], acc[mt][nt]);
            }
        }
        __syncthreads();
    }
#pragma unroll
    for (int mt = 0; mt < 2; ++mt)
#pragma unroll
        for (int nt = 0; nt < 8; ++nt) {
            int crow = rowb + nt * 16 + lc;
            int ccol = colb + w * 32 + mt * 16 + quad * 4;
            u16x4 o;
            o[0] = f2bf(acc[mt][nt][0]); o[1] = f2bf(acc[mt][nt][1]);
            o[2] = f2bf(acc[mt][nt][2]); o[3] = f2bf(acc[mt][nt][3]);
            *(u16x4*)(outp + (size_t)crow * N + ccol) = o;
        }
}

// ------ pass 1: rdenl[bg][c2] = -ln( sum_r exp(q_r . k_c2 / 8) ) ------------
__global__ __launch_bounds__(256, 2) void k_pass1(const unsigned short* __restrict__ Pq,
                                                  const unsigned short* __restrict__ Pk,
                                                  float* __restrict__ rdenl) {
    __shared__ __align__(16) unsigned short qs[128][72];
    __shared__ __align__(16) unsigned short kss[128][72];
    __shared__ float dsum[4][128];
    const int tid = threadIdx.x;
    const int lane = tid & 63, w = tid >> 6;
    const int lc = lane & 15, quad = lane >> 4;
    const int c2b = blockIdx.x * 128;
    const int bg  = blockIdx.y;
    const unsigned short* qbase = Pq + (size_t)bg * 131072;
    const unsigned short* kbase = Pk + (size_t)bg * 131072 + (size_t)c2b * 64;

#pragma unroll
    for (int p = 0; p < 4; ++p) {      // k tile: 128 rows x 64, contiguous
        int v = tid + p * 256;
        int r = v >> 3, s = (v & 7) * 8;
        *(u16x8*)(&kss[r][s]) = *(const u16x8*)(kbase + (size_t)v * 8);
    }

    float csum[8];
#pragma unroll
    for (int nt = 0; nt < 8; ++nt) csum[nt] = 0.f;

    for (int it = 0; it < 16; ++it) {
        __syncthreads();
        const unsigned short* qit = qbase + (size_t)it * 8192;
#pragma unroll
        for (int p = 0; p < 4; ++p) {
            int v = tid + p * 256;
            int r = v >> 3, s = (v & 7) * 8;
            *(u16x8*)(&qs[r][s]) = *(const u16x8*)(qit + (size_t)v * 8);
        }
        __syncthreads();

        f4v sc[2][8];
#pragma unroll
        for (int mt = 0; mt < 2; ++mt)
#pragma unroll
            for (int nt = 0; nt < 8; ++nt) sc[mt][nt] = f4v{0.f, 0.f, 0.f, 0.f};
#pragma unroll
        for (int ks = 0; ks < 2; ++ks) {
            int kk = ks * 32 + quad * 8;
            bf8v bk[8];
#pragma unroll
            for (int nt = 0; nt < 8; ++nt) bk[nt] = *(const bf8v*)(&kss[nt * 16 + lc][kk]);
#pragma unroll
            for (int mt = 0; mt < 2; ++mt) {
                bf8v a = *(const bf8v*)(&qs[w * 32 + mt * 16 + lc][kk]);
#pragma unroll
                for (int nt = 0; nt < 8; ++nt) sc[mt][nt] = MFMA32(a, bk[nt], sc[mt][nt]);
            }
        }
#pragma unroll
        for (int mt = 0; mt < 2; ++mt)
#pragma unroll
            for (int nt = 0; nt < 8; ++nt)
#pragma unroll
                for (int r = 0; r < 4; ++r)
                    csum[nt] += __expf(sc[mt][nt][r] * 0.125f);
    }

#pragma unroll
    for (int nt = 0; nt < 8; ++nt) {   // reduce across quads (rows live in regs+quads)
        float v = csum[nt];
        v += __shfl_xor(v, 16, 64);
        v += __shfl_xor(v, 32, 64);
        if (quad == 0) dsum[w][nt * 16 + lc] = v;
    }
    __syncthreads();
    if (tid < 128) {
        float tot = dsum[0][tid] + dsum[1][tid] + dsum[2][tid] + dsum[3][tid];
        rdenl[(size_t)bg * 2048 + c2b + tid] = -__logf(tot);
    }
}

// --------- pass 2: out[b, g*256+j, h, :] = P_{bg}[j*8+h, :] @ v_{b,h} -------
// S^T D-frag (c2=quad*4+reg, r=lc) == 16x16x16bf16_1k B-frag (k=quad*4+j, n=lc):
// exp(S) flows register->MFMA with no LDS round-trip.
__global__ __launch_bounds__(256, 3) void k_pass2(const unsigned short* __restrict__ Pq,
                                                  const unsigned short* __restrict__ Pk,
                                                  const unsigned short* __restrict__ Vt,
                                                  const float* __restrict__ rdenl,
                                                  float* __restrict__ out) {
    __shared__ __align__(16) unsigned short qs[128][72];   // q_sub rows (stride-8 gather)
    __shared__ __align__(16) unsigned short kss[64][72];   // k chunk [c2=64][64]
    __shared__ __align__(16) unsigned short vs[128][72];   // v^T chunk [d=128][c2=64]
    const int tid = threadIdx.x;
    const int lane = tid & 63, w = tid >> 6;
    const int lc = lane & 15, quad = lane >> 4;
    const int jt = blockIdx.x, h = blockIdx.y, bg = blockIdx.z;
    const int b = bg >> 3, g = bg & 7;

    const unsigned short* qbase = Pq + (size_t)bg * 131072;
    const unsigned short* kbase = Pk + (size_t)bg * 131072;
    const unsigned short* vbase = Vt + (size_t)(b * 8 + h) * 262144;
    const float* rdl = rdenl + (size_t)bg * 2048;

#pragma unroll
    for (int p = 0; p < 4; ++p) {      // q_sub: row i <- global q row (jt*128+i)*8 + h
        int v = tid + p * 256;
        int i = v >> 3, s = (v & 7) * 8;
        *(u16x8*)(&qs[i][s]) =
            *(const u16x8*)(qbase + (size_t)((jt * 128 + i) * 8 + h) * 64 + s);
    }
    __syncthreads();

    // preload q B-frags to registers; qs never read again
    bf8v bq[2][2];
#pragma unroll
    for (int nt = 0; nt < 2; ++nt)
#pragma unroll
        for (int ks = 0; ks < 2; ++ks)
            bq[nt][ks] = *(const bf8v*)(&qs[w * 32 + nt * 16 + lc][ks * 32 + quad * 8]);

    f4v acc[8][2];
#pragma unroll
    for (int dt = 0; dt < 8; ++dt)
#pragma unroll
        for (int nt = 0; nt < 2; ++nt) acc[dt][nt] = f4v{0.f, 0.f, 0.f, 0.f};

    for (int cc = 0; cc < 32; ++cc) {
        const int c2b = cc * 64;
        __syncthreads();               // prev-iter kss/vs readers done
#pragma unroll
        for (int p = 0; p < 2; ++p) {  // k chunk: 64x64 contiguous
            int v = tid + p * 256;
            int r = v >> 3, s = (v & 7) * 8;
            *(u16x8*)(&kss[r][s]) = *(const u16x8*)(kbase + (size_t)c2b * 64 + v * 8);
        }
#pragma unroll
        for (int p = 0; p < 4; ++p) {  // v^T chunk: 128 d x 64 c2
            int v = tid + p * 256;
            int d = v >> 3, s = (v & 7) * 8;
            *(u16x8*)(&vs[d][s]) = *(const u16x8*)(vbase + (size_t)d * 2048 + c2b + s);
        }
        __syncthreads();

        // S^T: D[m=c2 64][n=r 32/wave], A=kss, B=bq (regs)
        f4v sc[4][2];
#pragma unroll
        for (int mt = 0; mt < 4; ++mt)
#pragma unroll
            for (int nt = 0; nt < 2; ++nt) sc[mt][nt] = f4v{0.f, 0.f, 0.f, 0.f};
#pragma unroll
        for (int ks = 0; ks < 2; ++ks) {
            int kk = ks * 32 + quad * 8;
            bf8v a[4];
#pragma unroll
            for (int mt = 0; mt < 4; ++mt) a[mt] = *(const bf8v*)(&kss[mt * 16 + lc][kk]);
#pragma unroll
            for (int mt = 0; mt < 4; ++mt)
#pragma unroll
                for (int nt = 0; nt < 2; ++nt)
                    sc[mt][nt] = MFMA32(a[mt], bq[nt][ks], sc[mt][nt]);
        }

        // P^T = exp(S^T/8 - ln colsum), packed per-lane into x16 B-frags
        bf4v pb[4][2];
#pragma unroll
        for (int mt = 0; mt < 4; ++mt) {
            f4v lrd = *(const f4v*)(rdl + c2b + mt * 16 + quad * 4);
#pragma unroll
            for (int nt = 0; nt < 2; ++nt)
#pragma unroll
                for (int i = 0; i < 4; ++i)
                    pb[mt][nt][i] =
                        (short)f2bf(__expf(sc[mt][nt][i] * 0.125f + lrd[i]));
        }

        // PV: Out^T[d 128][r 32/wave] += v'^T[d][c2] @ P^T[c2][r], K=16 MFMA
#pragma unroll
        for (int mt = 0; mt < 4; ++mt)
#pragma unroll
            for (int dt = 0; dt < 8; ++dt) {
                bf4v a = *(const bf4v*)(&vs[dt * 16 + lc][mt * 16 + quad * 4]);
#pragma unroll
                for (int nt = 0; nt < 2; ++nt)
                    acc[dt][nt] = MFMA16(a, pb[mt][nt], acc[dt][nt]);
            }
    }

    // epilogue: d = dt*16+quad*4+reg (4 consecutive), r = w*32+nt*16+lc
    float* ob = out + (size_t)(b * 2048 + g * 256 + jt * 128) * 1024 + h * 128;
#pragma unroll
    for (int dt = 0; dt < 8; ++dt)
#pragma unroll
        for (int nt = 0; nt < 2; ++nt) {
            int r = w * 32 + nt * 16 + lc;
            int d = dt * 16 + quad * 4;
            *(f4v*)(ob + (size_t)r * 1024 + d) = acc[dt][nt];
        }
}

// ---------------------------------------------------------------------------
extern "C" void kernel_launch(void* const* d_in, const int* in_sizes, int n_in,
                              void* d_out, int out_size, void* d_ws, size_t ws_size,
                              hipStream_t stream) {
    const float* x  = (const float*)d_in[0];   // [4][2048][1024]
    const float* Mq = (const float*)d_in[1];   // [1024][512]
    const float* Mk = (const float*)d_in[2];   // [1024][512]
    const float* Mv = (const float*)d_in[3];   // [1024][1024]
    float* out = (float*)d_out;                // [4][2048][1024]

    char* base = (char*)d_ws;
    unsigned short* xb  = (unsigned short*)base;  base += 16777216;  // x bf16
    unsigned short* wqt = (unsigned short*)base;  base += 1048576;   // Mq^T [512][1024]
    unsigned short* wkt = (unsigned short*)base;  base += 1048576;   // Mk^T (contig after wqt)
    unsigned short* wvt = (unsigned short*)base;  base += 2097152;   // Mv^T [1024][1024]
    unsigned short* pq  = (unsigned short*)base;  base += 8388608;   // [4*2048][512]
    unsigned short* pk  = (unsigned short*)base;  base += 8388608;
    unsigned short* pv  = (unsigned short*)base;  base += 16777216;  // [4*2048][1024]
    unsigned short* vt  = (unsigned short*)base;  base += 16777216;  // [32][128][2048]
    float* rdenl = (float*)base;                  base += 262144;    // [32][2048] = -ln colsum

    k_cvt<<<8192, 256, 0, stream>>>(x, xb, 2097152);
    k_cvtT3<<<dim3(16, 16, 2), 256, 0, stream>>>(Mq, Mk, Mv, wqt, wkt, wvt);
    k_gemm<<<dim3(64, 16), 256, 0, stream>>>(xb, wqt /* = Wt[2048][1024] */, pq, pk, pv);
    k_T<<<dim3(2, 32, 32), 256, 0, stream>>>(pv, vt);
    k_pass1<<<dim3(16, 32), 256, 0, stream>>>(pq, pk, rdenl);
    k_pass2<<<dim3(2, 8, 32), 256, 0, stream>>>(pq, pk, vt, rdenl, out);
}

// Round 4
// 254.199 us; speedup vs baseline: 1.2117x; 1.2117x over previous
//
#include <hip/hip_runtime.h>
#include <stdint.h>
#include <stddef.h>

// ---------------------------------------------------------------------------
// MultiHeadAttentionBlock: B=4, C=2048, D=1024, H=8, K=64, V=128
//
//   q_{b,g}[r][k]  = Pq[b*2048 + g*256 + r/8][(r%8)*64 + k]   (contiguous [2048,64])
//   out[b, c, h, d] = sum_c2 att_{b,g=c/256}[r=(c%256)*8+h][c2] * v_{b,h}[c2][d]
//   att[r][c2] = exp(s[r][c2]/8) / sum_r' exp(s[r'][c2]/8)    (softmax over r)
//
// R4: pass2 with permuted-A S^T -> full-rate MFMA32 everywhere.
//  * S^T tiles read kss A-rows permuted: tile mt, lane lc reads row
//    c2 = (mt>>1)*32 + (lc>>2)*8 + (mt&1)*4 + (lc&3). Then D(quad,reg) holds
//    c2 = (mt>>1)*32 + quad*8 + (mt&1)*4 + reg, so tiles (2kc,2kc+1) concat
//    into exactly the x32 B-frag (k=quad*8+j) for PV. No LDS round-trip,
//    no shuffles, no half-rate K=16 MFMA (R3's mistake: 16x16x16bf16_1k
//    is half-rate; 16x16x32 is the gfx950 full-rate shape).
//  * kss columns XOR-swizzled (c8 += rlog>>3 mod 8) so permuted A-reads
//    stay conflict-free.
//  * kss/vs double-buffered (72 KB LDS total, 2 blocks/CU = grid anyway):
//    one barrier per cc, next-chunk global loads issued before compute.
// ---------------------------------------------------------------------------

typedef short     bf8v  __attribute__((ext_vector_type(8)));   // 8 x bf16 (x32 A/B frag)
typedef float     f4v   __attribute__((ext_vector_type(4)));   // 4 x f32 (C/D frag)
typedef unsigned short u16x4 __attribute__((ext_vector_type(4)));
typedef unsigned short u16x8 __attribute__((ext_vector_type(8)));

__device__ __forceinline__ unsigned short f2bf(float f) {  // RNE f32->bf16
    union { float f; uint32_t u; } v; v.f = f;
    return (unsigned short)((v.u + 0x7fffu + ((v.u >> 16) & 1u)) >> 16);
}

#define MFMA32(A, B, C) __builtin_amdgcn_mfma_f32_16x16x32_bf16((A), (B), (C), 0, 0, 0)

// -------------------- fp32 -> bf16 elementwise convert ----------------------
__global__ __launch_bounds__(256) void k_cvt(const float* __restrict__ in,
                                             unsigned short* __restrict__ out, int n4) {
    int i = blockIdx.x * 256 + threadIdx.x;
    if (i >= n4) return;
    f4v v = *(const f4v*)(in + (size_t)i * 4);
    u16x4 o;
    o[0] = f2bf(v[0]); o[1] = f2bf(v[1]); o[2] = f2bf(v[2]); o[3] = f2bf(v[3]);
    *(u16x4*)(out + (size_t)i * 4) = o;
}

// ---- fp32 [1024][N] -> bf16 transposed [N][1024], all 3 weights fused ------
__global__ __launch_bounds__(256) void k_cvtT3(const float* __restrict__ Mq,
                                               const float* __restrict__ Mk,
                                               const float* __restrict__ Mv,
                                               unsigned short* __restrict__ wqt,
                                               unsigned short* __restrict__ wkt,
                                               unsigned short* __restrict__ wvt) {
    __shared__ unsigned short t[64][68];
    const int tid = threadIdx.x;
    const int tr = tid >> 4, tc4 = (tid & 15) * 4;
    const float* in; unsigned short* outT; int Ncols, cb;
    if (blockIdx.z == 0) {
        if (blockIdx.x < 8) { in = Mq; outT = wqt; Ncols = 512; cb = blockIdx.x * 64; }
        else                { in = Mk; outT = wkt; Ncols = 512; cb = (blockIdx.x - 8) * 64; }
    } else                  { in = Mv; outT = wvt; Ncols = 1024; cb = blockIdx.x * 64; }
    const int rb = blockIdx.y * 64;
#pragma unroll
    for (int p = 0; p < 4; ++p) {
        int r = tr + p * 16;
        f4v v = *(const f4v*)(in + (size_t)(rb + r) * Ncols + cb + tc4);
        t[r][tc4 + 0] = f2bf(v[0]); t[r][tc4 + 1] = f2bf(v[1]);
        t[r][tc4 + 2] = f2bf(v[2]); t[r][tc4 + 3] = f2bf(v[3]);
    }
    __syncthreads();
#pragma unroll
    for (int p = 0; p < 4; ++p) {
        int r = tr + p * 16;               // output row = input col cb + r
        u16x4 o;
        o[0] = t[tc4 + 0][r]; o[1] = t[tc4 + 1][r];
        o[2] = t[tc4 + 2][r]; o[3] = t[tc4 + 3][r];
        *(u16x4*)(outT + (size_t)(cb + r) * 1024 + rb + tc4) = o;
    }
}

// -------- bf16 transpose [2048][128] -> [128][2048], 32 batches (b,h) -------
__global__ __launch_bounds__(256) void k_T(const unsigned short* __restrict__ in,
                                           unsigned short* __restrict__ out) {
    __shared__ unsigned short t[64][68];
    const int tid = threadIdx.x;
    const int tr = tid >> 4, tc4 = (tid & 15) * 4;
    const int rb = blockIdx.y * 64, cb = blockIdx.x * 64;
    const unsigned short* ib = in  + (size_t)blockIdx.z * 262144;
    unsigned short*       ob = out + (size_t)blockIdx.z * 262144;
#pragma unroll
    for (int p = 0; p < 4; ++p) {
        int r = tr + p * 16;
        u16x4 v = *(const u16x4*)(ib + (size_t)(rb + r) * 128 + cb + tc4);
        t[r][tc4 + 0] = v[0]; t[r][tc4 + 1] = v[1];
        t[r][tc4 + 2] = v[2]; t[r][tc4 + 3] = v[3];
    }
    __syncthreads();
#pragma unroll
    for (int p = 0; p < 4; ++p) {
        int r = tr + p * 16;
        u16x4 o;
        o[0] = t[tc4 + 0][r]; o[1] = t[tc4 + 1][r];
        o[2] = t[tc4 + 2][r]; o[3] = t[tc4 + 3][r];
        *(u16x4*)(ob + (size_t)(cb + r) * 2048 + rb + tc4) = o;
    }
}

// ------- fused projection GEMM: {Pq,Pk,Pv} = Xb[8192][1024] @ {Mq,Mk,Mv} ----
// Wt = [2048][1024] (wqt|wkt|wvt stacked). Computed as C^T: 4 regs = 4 cols.
__global__ __launch_bounds__(256, 2) void k_gemm(const unsigned short* __restrict__ X,
                                                 const unsigned short* __restrict__ Wt,
                                                 unsigned short* __restrict__ pq,
                                                 unsigned short* __restrict__ pk,
                                                 unsigned short* __restrict__ pv) {
    __shared__ __align__(16) unsigned short xs[128][72];
    __shared__ __align__(16) unsigned short wls[128][72];
    const int tid = threadIdx.x;
    const int lane = tid & 63, w = tid >> 6;
    const int lc = lane & 15, quad = lane >> 4;
    const int rowb = blockIdx.x * 128, cb = blockIdx.y;

    unsigned short* outp; int N, colb;
    if (cb < 4)      { outp = pq; N = 512;  colb = cb * 128; }
    else if (cb < 8) { outp = pk; N = 512;  colb = (cb - 4) * 128; }
    else             { outp = pv; N = 1024; colb = (cb - 8) * 128; }

    f4v acc[2][8];
#pragma unroll
    for (int mt = 0; mt < 2; ++mt)
#pragma unroll
        for (int nt = 0; nt < 8; ++nt) acc[mt][nt] = f4v{0.f, 0.f, 0.f, 0.f};

    for (int k0 = 0; k0 < 1024; k0 += 64) {
#pragma unroll
        for (int p = 0; p < 4; ++p) {
            int v = tid + p * 256;
            int r = v >> 3, s = (v & 7) * 8;
            *(u16x8*)(&xs[r][s])  = *(const u16x8*)(X  + (size_t)(rowb + r) * 1024 + k0 + s);
            *(u16x8*)(&wls[r][s]) = *(const u16x8*)(Wt + (size_t)(cb * 128 + r) * 1024 + k0 + s);
        }
        __syncthreads();
#pragma unroll
        for (int ks = 0; ks < 2; ++ks) {
            int kk = ks * 32 + quad * 8;
            bf8v bx[8];
#pragma unroll
            for (int nt = 0; nt < 8; ++nt) bx[nt] = *(const bf8v*)(&xs[nt * 16 + lc][kk]);
#pragma unroll
            for (int mt = 0; mt < 2; ++mt) {
                bf8v a = *(const bf8v*)(&wls[w * 32 + mt * 16 + lc][kk]);
#pragma unroll
                for (int nt = 0; nt < 8; ++nt) acc[mt][nt] = MFMA32(a, bx[nt], acc[mt][nt]);
            }
        }
        __syncthreads();
    }
#pragma unroll
    for (int mt = 0; mt < 2; ++mt)
#pragma unroll
        for (int nt = 0; nt < 8; ++nt) {
            int crow = rowb + nt * 16 + lc;
            int ccol = colb + w * 32 + mt * 16 + quad * 4;
            u16x4 o;
            o[0] = f2bf(acc[mt][nt][0]); o[1] = f2bf(acc[mt][nt][1]);
            o[2] = f2bf(acc[mt][nt][2]); o[3] = f2bf(acc[mt][nt][3]);
            *(u16x4*)(outp + (size_t)crow * N + ccol) = o;
        }
}

// ------ pass 1: rdenl[bg][c2] = -ln( sum_r exp(q_r . k_c2 / 8) ) ------------
__global__ __launch_bounds__(256, 2) void k_pass1(const unsigned short* __restrict__ Pq,
                                                  const unsigned short* __restrict__ Pk,
                                                  float* __restrict__ rdenl) {
    __shared__ __align__(16) unsigned short qs[128][72];
    __shared__ __align__(16) unsigned short kss[128][72];
    __shared__ float dsum[4][128];
    const int tid = threadIdx.x;
    const int lane = tid & 63, w = tid >> 6;
    const int lc = lane & 15, quad = lane >> 4;
    const int c2b = blockIdx.x * 128;
    const int bg  = blockIdx.y;
    const unsigned short* qbase = Pq + (size_t)bg * 131072;
    const unsigned short* kbase = Pk + (size_t)bg * 131072 + (size_t)c2b * 64;

#pragma unroll
    for (int p = 0; p < 4; ++p) {      // k tile: 128 rows x 64, contiguous
        int v = tid + p * 256;
        int r = v >> 3, s = (v & 7) * 8;
        *(u16x8*)(&kss[r][s]) = *(const u16x8*)(kbase + (size_t)v * 8);
    }

    float csum[8];
#pragma unroll
    for (int nt = 0; nt < 8; ++nt) csum[nt] = 0.f;

    for (int it = 0; it < 16; ++it) {
        __syncthreads();
        const unsigned short* qit = qbase + (size_t)it * 8192;
#pragma unroll
        for (int p = 0; p < 4; ++p) {
            int v = tid + p * 256;
            int r = v >> 3, s = (v & 7) * 8;
            *(u16x8*)(&qs[r][s]) = *(const u16x8*)(qit + (size_t)v * 8);
        }
        __syncthreads();

        f4v sc[2][8];
#pragma unroll
        for (int mt = 0; mt < 2; ++mt)
#pragma unroll
            for (int nt = 0; nt < 8; ++nt) sc[mt][nt] = f4v{0.f, 0.f, 0.f, 0.f};
#pragma unroll
        for (int ks = 0; ks < 2; ++ks) {
            int kk = ks * 32 + quad * 8;
            bf8v bk[8];
#pragma unroll
            for (int nt = 0; nt < 8; ++nt) bk[nt] = *(const bf8v*)(&kss[nt * 16 + lc][kk]);
#pragma unroll
            for (int mt = 0; mt < 2; ++mt) {
                bf8v a = *(const bf8v*)(&qs[w * 32 + mt * 16 + lc][kk]);
#pragma unroll
                for (int nt = 0; nt < 8; ++nt) sc[mt][nt] = MFMA32(a, bk[nt], sc[mt][nt]);
            }
        }
#pragma unroll
        for (int mt = 0; mt < 2; ++mt)
#pragma unroll
            for (int nt = 0; nt < 8; ++nt)
#pragma unroll
                for (int r = 0; r < 4; ++r)
                    csum[nt] += __expf(sc[mt][nt][r] * 0.125f);
    }

#pragma unroll
    for (int nt = 0; nt < 8; ++nt) {   // reduce across quads (rows live in regs+quads)
        float v = csum[nt];
        v += __shfl_xor(v, 16, 64);
        v += __shfl_xor(v, 32, 64);
        if (quad == 0) dsum[w][nt * 16 + lc] = v;
    }
    __syncthreads();
    if (tid < 128) {
        float tot = dsum[0][tid] + dsum[1][tid] + dsum[2][tid] + dsum[3][tid];
        rdenl[(size_t)bg * 2048 + c2b + tid] = -__logf(tot);
    }
}

// --------- pass 2: out[b, g*256+j, h, :] = P_{bg}[j*8+h, :] @ v_{b,h} -------
__global__ __launch_bounds__(256, 2) void k_pass2(const unsigned short* __restrict__ Pq,
                                                  const unsigned short* __restrict__ Pk,
                                                  const unsigned short* __restrict__ Vt,
                                                  const float* __restrict__ rdenl,
                                                  float* __restrict__ out) {
    __shared__ __align__(16) unsigned short qs[128][72];      // q_sub rows (one-shot)
    __shared__ __align__(16) unsigned short kss[2][64][72];   // k dbuf [c2][qk], swizzled cols
    __shared__ __align__(16) unsigned short vs[2][128][72];   // v^T dbuf [d][c2]
    const int tid = threadIdx.x;
    const int lane = tid & 63, w = tid >> 6;
    const int lc = lane & 15, quad = lane >> 4;
    const int jt = blockIdx.x, h = blockIdx.y, bg = blockIdx.z;
    const int b = bg >> 3, g = bg & 7;

    const unsigned short* qbase = Pq + (size_t)bg * 131072;
    const unsigned short* kbase = Pk + (size_t)bg * 131072;
    const unsigned short* vbase = Vt + (size_t)(b * 8 + h) * 262144;
    const float* rdl = rdenl + (size_t)bg * 2048;

#pragma unroll
    for (int p = 0; p < 4; ++p) {      // q_sub: row i <- global q row (jt*128+i)*8 + h
        int v = tid + p * 256;
        int i = v >> 3, s = (v & 7) * 8;
        *(u16x8*)(&qs[i][s]) =
            *(const u16x8*)(qbase + (size_t)((jt * 128 + i) * 8 + h) * 64 + s);
    }
    // prologue: stage chunk 0 into buf 0 (kss swizzled: c8 -> (c8 + row>>3) & 7)
#pragma unroll
    for (int p = 0; p < 2; ++p) {
        int v = tid + p * 256;                 // v in [0,512): r=v>>3, s8=v&7
        int c8 = ((v & 7) + (v >> 6)) & 7;
        *(u16x8*)(&kss[0][v >> 3][c8 * 8]) = *(const u16x8*)(kbase + (size_t)v * 8);
    }
#pragma unroll
    for (int p = 0; p < 4; ++p) {
        int v = tid + p * 256;
        int d = v >> 3, s = (v & 7) * 8;
        *(u16x8*)(&vs[0][d][s]) = *(const u16x8*)(vbase + (size_t)d * 2048 + s);
    }
    __syncthreads();

    // preload q B-frags to registers; qs dead afterwards
    bf8v bq[2][2];
#pragma unroll
    for (int nt = 0; nt < 2; ++nt)
#pragma unroll
        for (int ks = 0; ks < 2; ++ks)
            bq[nt][ks] = *(const bf8v*)(&qs[w * 32 + nt * 16 + lc][ks * 32 + quad * 8]);

    f4v acc[8][2];
#pragma unroll
    for (int dt = 0; dt < 8; ++dt)
#pragma unroll
        for (int nt = 0; nt < 2; ++nt) acc[dt][nt] = f4v{0.f, 0.f, 0.f, 0.f};

    for (int cc = 0; cc < 32; ++cc) {
        const int buf = cc & 1;
        // ---- issue next-chunk global loads (latency hidden by compute) ----
        u16x8 kreg[2], vreg[4];
        if (cc < 31) {
            const int c2n = (cc + 1) * 64;
#pragma unroll
            for (int p = 0; p < 2; ++p) {
                int v = tid + p * 256;
                kreg[p] = *(const u16x8*)(kbase + (size_t)c2n * 64 + (size_t)v * 8);
            }
#pragma unroll
            for (int p = 0; p < 4; ++p) {
                int v = tid + p * 256;
                vreg[p] = *(const u16x8*)(vbase + (size_t)(v >> 3) * 2048 + c2n + (v & 7) * 8);
            }
        }

        // ---- S^T with permuted A rows: sc[mt] D(quad,reg) holds
        //      c2 = (mt>>1)*32 + quad*8 + (mt&1)*4 + reg
        f4v sc[4][2];
#pragma unroll
        for (int mt = 0; mt < 4; ++mt)
#pragma unroll
            for (int nt = 0; nt < 2; ++nt) sc[mt][nt] = f4v{0.f, 0.f, 0.f, 0.f};
#pragma unroll
        for (int ks = 0; ks < 2; ++ks) {
            bf8v a[4];
#pragma unroll
            for (int mt = 0; mt < 4; ++mt) {
                int rlog = ((mt >> 1) << 5) + ((lc >> 2) << 3) + ((mt & 1) << 2) + (lc & 3);
                int c8   = ((ks << 2) + quad + ((mt >> 1) << 2) + (lc >> 2)) & 7;  // swizzle
                a[mt] = *(const bf8v*)(&kss[buf][rlog][c8 * 8]);
            }
#pragma unroll
            for (int mt = 0; mt < 4; ++mt)
#pragma unroll
                for (int nt = 0; nt < 2; ++nt)
                    sc[mt][nt] = MFMA32(a[mt], bq[nt][ks], sc[mt][nt]);
        }

        // ---- P^T = exp(S^T/8 - ln colsum), packed straight into x32 B-frags
        bf8v pb[2][2];
#pragma unroll
        for (int mt = 0; mt < 4; ++mt) {
            f4v lrd = *(const f4v*)(rdl + cc * 64 + ((mt >> 1) << 5) + (quad << 3) + ((mt & 1) << 2));
#pragma unroll
            for (int nt = 0; nt < 2; ++nt)
#pragma unroll
                for (int i = 0; i < 4; ++i)
                    pb[mt >> 1][nt][(mt & 1) * 4 + i] =
                        (short)f2bf(__expf(__builtin_fmaf(sc[mt][nt][i], 0.125f, lrd[i])));
        }

        // ---- PV: Out^T[d][r] += v^T[d][c2] @ P^T[c2][r], full-rate x32
#pragma unroll
        for (int kc = 0; kc < 2; ++kc)
#pragma unroll
            for (int dt = 0; dt < 8; ++dt) {
                bf8v a = *(const bf8v*)(&vs[buf][dt * 16 + lc][kc * 32 + quad * 8]);
#pragma unroll
                for (int nt = 0; nt < 2; ++nt)
                    acc[dt][nt] = MFMA32(a, pb[kc][nt], acc[dt][nt]);
            }

        // ---- write next chunk into the other buffer, single barrier ----
        if (cc < 31) {
            const int nbuf = buf ^ 1;
#pragma unroll
            for (int p = 0; p < 2; ++p) {
                int v = tid + p * 256;
                int c8 = ((v & 7) + (v >> 6)) & 7;
                *(u16x8*)(&kss[nbuf][v >> 3][c8 * 8]) = kreg[p];
            }
#pragma unroll
            for (int p = 0; p < 4; ++p) {
                int v = tid + p * 256;
                *(u16x8*)(&vs[nbuf][v >> 3][(v & 7) * 8]) = vreg[p];
            }
        }
        __syncthreads();
    }

    // epilogue: d = dt*16+quad*4+reg (4 consecutive), r = w*32+nt*16+lc
    float* ob = out + (size_t)(b * 2048 + g * 256 + jt * 128) * 1024 + h * 128;
#pragma unroll
    for (int dt = 0; dt < 8; ++dt)
#pragma unroll
        for (int nt = 0; nt < 2; ++nt) {
            int r = w * 32 + nt * 16 + lc;
            int d = dt * 16 + quad * 4;
            *(f4v*)(ob + (size_t)r * 1024 + d) = acc[dt][nt];
        }
}

// ---------------------------------------------------------------------------
extern "C" void kernel_launch(void* const* d_in, const int* in_sizes, int n_in,
                              void* d_out, int out_size, void* d_ws, size_t ws_size,
                              hipStream_t stream) {
    const float* x  = (const float*)d_in[0];   // [4][2048][1024]
    const float* Mq = (const float*)d_in[1];   // [1024][512]
    const float* Mk = (const float*)d_in[2];   // [1024][512]
    const float* Mv = (const float*)d_in[3];   // [1024][1024]
    float* out = (float*)d_out;                // [4][2048][1024]

    char* base = (char*)d_ws;
    unsigned short* xb  = (unsigned short*)base;  base += 16777216;  // x bf16
    unsigned short* wqt = (unsigned short*)base;  base += 1048576;   // Mq^T [512][1024]
    unsigned short* wkt = (unsigned short*)base;  base += 1048576;   // Mk^T (contig after wqt)
    unsigned short* wvt = (unsigned short*)base;  base += 2097152;   // Mv^T [1024][1024]
    unsigned short* pq  = (unsigned short*)base;  base += 8388608;   // [4*2048][512]
    unsigned short* pk  = (unsigned short*)base;  base += 8388608;
    unsigned short* pv  = (unsigned short*)base;  base += 16777216;  // [4*2048][1024]
    unsigned short* vt  = (unsigned short*)base;  base += 16777216;  // [32][128][2048]
    float* rdenl = (float*)base;                  base += 262144;    // [32][2048] = -ln colsum

    k_cvt<<<8192, 256, 0, stream>>>(x, xb, 2097152);
    k_cvtT3<<<dim3(16, 16, 2), 256, 0, stream>>>(Mq, Mk, Mv, wqt, wkt, wvt);
    k_gemm<<<dim3(64, 16), 256, 0, stream>>>(xb, wqt /* = Wt[2048][1024] */, pq, pk, pv);
    k_T<<<dim3(2, 32, 32), 256, 0, stream>>>(pv, vt);
    k_pass1<<<dim3(16, 32), 256, 0, stream>>>(pq, pk, rdenl);
    k_pass2<<<dim3(2, 8, 32), 256, 0, stream>>>(pq, pk, vt, rdenl, out);
}

// Round 5
// 230.355 us; speedup vs baseline: 1.3372x; 1.1035x over previous
//
#include <hip/hip_runtime.h>
#include <stdint.h>
#include <stddef.h>

// ---------------------------------------------------------------------------
// MultiHeadAttentionBlock: B=4, C=2048, D=1024, H=8, K=64, V=128
//
//   q_{b,g}[r][k]  = Pq[b*2048 + g*256 + r/8][(r%8)*64 + k]   (contiguous [2048,64])
//   out[b, c, h, d] = sum_c2 att_{b,g=c/256}[r=(c%256)*8+h][c2] * v_{b,h}[c2][d]
//   att[r][c2] = exp(s[r][c2]/8) / sum_r' exp(s[r'][c2]/8)    (softmax over r)
//
// R5: m97-style staging for k_gemm and k_pass1 (the hidden 176us):
//  * global_load_lds width=16, double-buffered, 1 barrier per K-chunk.
//  * LDS tiles unpadded [128][64]; XOR chunk swizzle on the GLOBAL side
//    (lane i loads chunk (i&7)^(i>>3) of its row -> LDS(r,c8)=global(r,c8^(r&7)));
//    readers use c8' = (ks*4+quad)^(lc&7) -> conflict-free b128 reads.
//  * Pq pre-scaled by 0.125 in k_gemm epilogue (exact: power of two) ->
//    pass1 exp(s), pass2 exp(s+lrd), bit-identical output.
// pass2 (R4 permuted-A register-direct P) unchanged except fma->add.
// ---------------------------------------------------------------------------

typedef short     bf8v  __attribute__((ext_vector_type(8)));   // 8 x bf16 (x32 A/B frag)
typedef float     f4v   __attribute__((ext_vector_type(4)));   // 4 x f32 (C/D frag)
typedef unsigned short u16x4 __attribute__((ext_vector_type(4)));
typedef unsigned short u16x8 __attribute__((ext_vector_type(8)));

__device__ __forceinline__ unsigned short f2bf(float f) {  // RNE f32->bf16
    union { float f; uint32_t u; } v; v.f = f;
    return (unsigned short)((v.u + 0x7fffu + ((v.u >> 16) & 1u)) >> 16);
}

#define MFMA32(A, B, C) __builtin_amdgcn_mfma_f32_16x16x32_bf16((A), (B), (C), 0, 0, 0)
#define ASYNC16(g, l) __builtin_amdgcn_global_load_lds(                        \
    (const __attribute__((address_space(1))) unsigned int*)(g),                \
    (__attribute__((address_space(3))) unsigned int*)(l), 16, 0, 0)

// -------------------- fp32 -> bf16 elementwise convert ----------------------
__global__ __launch_bounds__(256) void k_cvt(const float* __restrict__ in,
                                             unsigned short* __restrict__ out, int n4) {
    int i = blockIdx.x * 256 + threadIdx.x;
    if (i >= n4) return;
    f4v v = *(const f4v*)(in + (size_t)i * 4);
    u16x4 o;
    o[0] = f2bf(v[0]); o[1] = f2bf(v[1]); o[2] = f2bf(v[2]); o[3] = f2bf(v[3]);
    *(u16x4*)(out + (size_t)i * 4) = o;
}

// ---- fp32 [1024][N] -> bf16 transposed [N][1024], all 3 weights fused ------
__global__ __launch_bounds__(256) void k_cvtT3(const float* __restrict__ Mq,
                                               const float* __restrict__ Mk,
                                               const float* __restrict__ Mv,
                                               unsigned short* __restrict__ wqt,
                                               unsigned short* __restrict__ wkt,
                                               unsigned short* __restrict__ wvt) {
    __shared__ unsigned short t[64][68];
    const int tid = threadIdx.x;
    const int tr = tid >> 4, tc4 = (tid & 15) * 4;
    const float* in; unsigned short* outT; int Ncols, cb;
    if (blockIdx.z == 0) {
        if (blockIdx.x < 8) { in = Mq; outT = wqt; Ncols = 512; cb = blockIdx.x * 64; }
        else                { in = Mk; outT = wkt; Ncols = 512; cb = (blockIdx.x - 8) * 64; }
    } else                  { in = Mv; outT = wvt; Ncols = 1024; cb = blockIdx.x * 64; }
    const int rb = blockIdx.y * 64;
#pragma unroll
    for (int p = 0; p < 4; ++p) {
        int r = tr + p * 16;
        f4v v = *(const f4v*)(in + (size_t)(rb + r) * Ncols + cb + tc4);
        t[r][tc4 + 0] = f2bf(v[0]); t[r][tc4 + 1] = f2bf(v[1]);
        t[r][tc4 + 2] = f2bf(v[2]); t[r][tc4 + 3] = f2bf(v[3]);
    }
    __syncthreads();
#pragma unroll
    for (int p = 0; p < 4; ++p) {
        int r = tr + p * 16;               // output row = input col cb + r
        u16x4 o;
        o[0] = t[tc4 + 0][r]; o[1] = t[tc4 + 1][r];
        o[2] = t[tc4 + 2][r]; o[3] = t[tc4 + 3][r];
        *(u16x4*)(outT + (size_t)(cb + r) * 1024 + rb + tc4) = o;
    }
}

// -------- bf16 transpose [2048][128] -> [128][2048], 32 batches (b,h) -------
__global__ __launch_bounds__(256) void k_T(const unsigned short* __restrict__ in,
                                           unsigned short* __restrict__ out) {
    __shared__ unsigned short t[64][68];
    const int tid = threadIdx.x;
    const int tr = tid >> 4, tc4 = (tid & 15) * 4;
    const int rb = blockIdx.y * 64, cb = blockIdx.x * 64;
    const unsigned short* ib = in  + (size_t)blockIdx.z * 262144;
    unsigned short*       ob = out + (size_t)blockIdx.z * 262144;
#pragma unroll
    for (int p = 0; p < 4; ++p) {
        int r = tr + p * 16;
        u16x4 v = *(const u16x4*)(ib + (size_t)(rb + r) * 128 + cb + tc4);
        t[r][tc4 + 0] = v[0]; t[r][tc4 + 1] = v[1];
        t[r][tc4 + 2] = v[2]; t[r][tc4 + 3] = v[3];
    }
    __syncthreads();
#pragma unroll
    for (int p = 0; p < 4; ++p) {
        int r = tr + p * 16;
        u16x4 o;
        o[0] = t[tc4 + 0][r]; o[1] = t[tc4 + 1][r];
        o[2] = t[tc4 + 2][r]; o[3] = t[tc4 + 3][r];
        *(u16x4*)(ob + (size_t)(cb + r) * 2048 + rb + tc4) = o;
    }
}

// ------- fused projection GEMM: {Pq,Pk,Pv} = Xb[8192][1024] @ {Mq,Mk,Mv} ----
// Wt = [2048][1024] stacked. global_load_lds dbuf staging, XOR-swizzled tiles.
__global__ __launch_bounds__(256, 2) void k_gemm(const unsigned short* __restrict__ X,
                                                 const unsigned short* __restrict__ Wt,
                                                 unsigned short* __restrict__ pq,
                                                 unsigned short* __restrict__ pk,
                                                 unsigned short* __restrict__ pv) {
    __shared__ __align__(16) unsigned short xs[2][8192];   // [128][64] swizzled
    __shared__ __align__(16) unsigned short ws2[2][8192];
    const int tid = threadIdx.x;
    const int lane = tid & 63, w = tid >> 6;
    const int lc = lane & 15, quad = lane >> 4;
    const int rowb = blockIdx.x * 128, cb = blockIdx.y;

    unsigned short* outp; int N, colb; float scale;
    if (cb < 4)      { outp = pq; N = 512;  colb = cb * 128;       scale = 0.125f; }
    else if (cb < 8) { outp = pk; N = 512;  colb = (cb - 4) * 128; scale = 1.0f; }
    else             { outp = pv; N = 1024; colb = (cb - 8) * 128; scale = 1.0f; }

    // lane-constant staging geometry: call j covers tile rows (w*4+j)*8 + lr
    const int lr   = lane >> 3;                 // 0..7
    const int swz  = ((lane & 7) ^ lr) * 8;     // swizzled chunk -> elem offset

    f4v acc[2][8];
#pragma unroll
    for (int mt = 0; mt < 2; ++mt)
#pragma unroll
        for (int nt = 0; nt < 8; ++nt) acc[mt][nt] = f4v{0.f, 0.f, 0.f, 0.f};

    // prologue: stage chunk 0 into buf 0
#pragma unroll
    for (int j = 0; j < 4; ++j) {
        int row = (w * 4 + j) * 8 + lr;
        ASYNC16(X  + (size_t)(rowb + row) * 1024 + swz,            &xs[0][(w * 4 + j) * 512]);
        ASYNC16(Wt + (size_t)(cb * 128 + row) * 1024 + swz,        &ws2[0][(w * 4 + j) * 512]);
    }
    __syncthreads();

    for (int k = 0; k < 16; ++k) {
        const int buf = k & 1;
        if (k < 15) {
            const int k0n = (k + 1) * 64;
#pragma unroll
            for (int j = 0; j < 4; ++j) {
                int row = (w * 4 + j) * 8 + lr;
                ASYNC16(X  + (size_t)(rowb + row) * 1024 + k0n + swz,     &xs[buf ^ 1][(w * 4 + j) * 512]);
                ASYNC16(Wt + (size_t)(cb * 128 + row) * 1024 + k0n + swz, &ws2[buf ^ 1][(w * 4 + j) * 512]);
            }
        }
#pragma unroll
        for (int ks = 0; ks < 2; ++ks) {
            bf8v bx[8];
#pragma unroll
            for (int nt = 0; nt < 8; ++nt) {
                int row = nt * 16 + lc;
                int c8  = (ks * 4 + quad) ^ (lc & 7);
                bx[nt] = *(const bf8v*)(&xs[buf][row * 64 + c8 * 8]);
            }
#pragma unroll
            for (int mt = 0; mt < 2; ++mt) {
                int row = w * 32 + mt * 16 + lc;
                int c8  = (ks * 4 + quad) ^ (lc & 7);
                bf8v a = *(const bf8v*)(&ws2[buf][row * 64 + c8 * 8]);
#pragma unroll
                for (int nt = 0; nt < 8; ++nt) acc[mt][nt] = MFMA32(a, bx[nt], acc[mt][nt]);
            }
        }
        __syncthreads();
    }
#pragma unroll
    for (int mt = 0; mt < 2; ++mt)
#pragma unroll
        for (int nt = 0; nt < 8; ++nt) {
            int crow = rowb + nt * 16 + lc;
            int ccol = colb + w * 32 + mt * 16 + quad * 4;
            u16x4 o;
            o[0] = f2bf(acc[mt][nt][0] * scale); o[1] = f2bf(acc[mt][nt][1] * scale);
            o[2] = f2bf(acc[mt][nt][2] * scale); o[3] = f2bf(acc[mt][nt][3] * scale);
            *(u16x4*)(outp + (size_t)crow * N + ccol) = o;
        }
}

// ------ pass 1: rdenl[bg][c2] = -ln( sum_r exp(q_r . k_c2) )  (q pre-scaled)
__global__ __launch_bounds__(256, 2) void k_pass1(const unsigned short* __restrict__ Pq,
                                                  const unsigned short* __restrict__ Pk,
                                                  float* __restrict__ rdenl) {
    __shared__ __align__(16) unsigned short kls[8192];      // k tile [128][64] swizzled
    __shared__ __align__(16) unsigned short qls[2][8192];   // q dbuf  [128][64] swizzled
    __shared__ float dsum[4][128];
    const int tid = threadIdx.x;
    const int lane = tid & 63, w = tid >> 6;
    const int lc = lane & 15, quad = lane >> 4;
    const int c2b = blockIdx.x * 128;
    const int bg  = blockIdx.y;
    const unsigned short* qbase = Pq + (size_t)bg * 131072;
    const unsigned short* kbase = Pk + (size_t)bg * 131072 + (size_t)c2b * 64;

    const int lr  = lane >> 3;
    const int swz = ((lane & 7) ^ lr) * 8;

    // prologue: k tile (once) + q tile 0 into buf 0
#pragma unroll
    for (int j = 0; j < 4; ++j) {
        int row = (w * 4 + j) * 8 + lr;
        ASYNC16(kbase + (size_t)row * 64 + swz, &kls[(w * 4 + j) * 512]);
        ASYNC16(qbase + (size_t)row * 64 + swz, &qls[0][(w * 4 + j) * 512]);
    }
    __syncthreads();

    float csum[8];
#pragma unroll
    for (int nt = 0; nt < 8; ++nt) csum[nt] = 0.f;

    for (int it = 0; it < 16; ++it) {
        const int buf = it & 1;
        if (it < 15) {
            const unsigned short* qn = qbase + (size_t)(it + 1) * 8192;
#pragma unroll
            for (int j = 0; j < 4; ++j) {
                int row = (w * 4 + j) * 8 + lr;
                ASYNC16(qn + (size_t)row * 64 + swz, &qls[buf ^ 1][(w * 4 + j) * 512]);
            }
        }

        f4v sc[2][8];
#pragma unroll
        for (int mt = 0; mt < 2; ++mt)
#pragma unroll
            for (int nt = 0; nt < 8; ++nt) sc[mt][nt] = f4v{0.f, 0.f, 0.f, 0.f};
#pragma unroll
        for (int ks = 0; ks < 2; ++ks) {
            bf8v bk[8];
#pragma unroll
            for (int nt = 0; nt < 8; ++nt) {
                int row = nt * 16 + lc;
                int c8  = (ks * 4 + quad) ^ (lc & 7);
                bk[nt] = *(const bf8v*)(&kls[row * 64 + c8 * 8]);
            }
#pragma unroll
            for (int mt = 0; mt < 2; ++mt) {
                int row = w * 32 + mt * 16 + lc;
                int c8  = (ks * 4 + quad) ^ (lc & 7);
                bf8v a = *(const bf8v*)(&qls[buf][row * 64 + c8 * 8]);
#pragma unroll
                for (int nt = 0; nt < 8; ++nt) sc[mt][nt] = MFMA32(a, bk[nt], sc[mt][nt]);
            }
        }
#pragma unroll
        for (int mt = 0; mt < 2; ++mt)
#pragma unroll
            for (int nt = 0; nt < 8; ++nt)
#pragma unroll
                for (int r = 0; r < 4; ++r)
                    csum[nt] += __expf(sc[mt][nt][r]);   // q pre-scaled by 1/8
        __syncthreads();
    }

#pragma unroll
    for (int nt = 0; nt < 8; ++nt) {   // reduce across quads (rows live in regs+quads)
        float v = csum[nt];
        v += __shfl_xor(v, 16, 64);
        v += __shfl_xor(v, 32, 64);
        if (quad == 0) dsum[w][nt * 16 + lc] = v;
    }
    __syncthreads();
    if (tid < 128) {
        float tot = dsum[0][tid] + dsum[1][tid] + dsum[2][tid] + dsum[3][tid];
        rdenl[(size_t)bg * 2048 + c2b + tid] = -__logf(tot);
    }
}

// --------- pass 2: out[b, g*256+j, h, :] = P_{bg}[j*8+h, :] @ v_{b,h} -------
__global__ __launch_bounds__(256, 2) void k_pass2(const unsigned short* __restrict__ Pq,
                                                  const unsigned short* __restrict__ Pk,
                                                  const unsigned short* __restrict__ Vt,
                                                  const float* __restrict__ rdenl,
                                                  float* __restrict__ out) {
    __shared__ __align__(16) unsigned short qs[128][72];      // q_sub rows (one-shot)
    __shared__ __align__(16) unsigned short kss[2][64][72];   // k dbuf [c2][qk], swizzled cols
    __shared__ __align__(16) unsigned short vs[2][128][72];   // v^T dbuf [d][c2]
    const int tid = threadIdx.x;
    const int lane = tid & 63, w = tid >> 6;
    const int lc = lane & 15, quad = lane >> 4;
    const int jt = blockIdx.x, h = blockIdx.y, bg = blockIdx.z;
    const int b = bg >> 3, g = bg & 7;

    const unsigned short* qbase = Pq + (size_t)bg * 131072;
    const unsigned short* kbase = Pk + (size_t)bg * 131072;
    const unsigned short* vbase = Vt + (size_t)(b * 8 + h) * 262144;
    const float* rdl = rdenl + (size_t)bg * 2048;

#pragma unroll
    for (int p = 0; p < 4; ++p) {      // q_sub: row i <- global q row (jt*128+i)*8 + h
        int v = tid + p * 256;
        int i = v >> 3, s = (v & 7) * 8;
        *(u16x8*)(&qs[i][s]) =
            *(const u16x8*)(qbase + (size_t)((jt * 128 + i) * 8 + h) * 64 + s);
    }
    // prologue: stage chunk 0 into buf 0 (kss swizzled: c8 -> (c8 + row>>3) & 7)
#pragma unroll
    for (int p = 0; p < 2; ++p) {
        int v = tid + p * 256;                 // v in [0,512): r=v>>3, s8=v&7
        int c8 = ((v & 7) + (v >> 6)) & 7;
        *(u16x8*)(&kss[0][v >> 3][c8 * 8]) = *(const u16x8*)(kbase + (size_t)v * 8);
    }
#pragma unroll
    for (int p = 0; p < 4; ++p) {
        int v = tid + p * 256;
        int d = v >> 3, s = (v & 7) * 8;
        *(u16x8*)(&vs[0][d][s]) = *(const u16x8*)(vbase + (size_t)d * 2048 + s);
    }
    __syncthreads();

    // preload q B-frags to registers; qs dead afterwards
    bf8v bq[2][2];
#pragma unroll
    for (int nt = 0; nt < 2; ++nt)
#pragma unroll
        for (int ks = 0; ks < 2; ++ks)
            bq[nt][ks] = *(const bf8v*)(&qs[w * 32 + nt * 16 + lc][ks * 32 + quad * 8]);

    f4v acc[8][2];
#pragma unroll
    for (int dt = 0; dt < 8; ++dt)
#pragma unroll
        for (int nt = 0; nt < 2; ++nt) acc[dt][nt] = f4v{0.f, 0.f, 0.f, 0.f};

    for (int cc = 0; cc < 32; ++cc) {
        const int buf = cc & 1;
        // ---- issue next-chunk global loads (latency hidden by compute) ----
        u16x8 kreg[2], vreg[4];
        if (cc < 31) {
            const int c2n = (cc + 1) * 64;
#pragma unroll
            for (int p = 0; p < 2; ++p) {
                int v = tid + p * 256;
                kreg[p] = *(const u16x8*)(kbase + (size_t)c2n * 64 + (size_t)v * 8);
            }
#pragma unroll
            for (int p = 0; p < 4; ++p) {
                int v = tid + p * 256;
                vreg[p] = *(const u16x8*)(vbase + (size_t)(v >> 3) * 2048 + c2n + (v & 7) * 8);
            }
        }

        // ---- S^T with permuted A rows: sc[mt] D(quad,reg) holds
        //      c2 = (mt>>1)*32 + quad*8 + (mt&1)*4 + reg
        f4v sc[4][2];
#pragma unroll
        for (int mt = 0; mt < 4; ++mt)
#pragma unroll
            for (int nt = 0; nt < 2; ++nt) sc[mt][nt] = f4v{0.f, 0.f, 0.f, 0.f};
#pragma unroll
        for (int ks = 0; ks < 2; ++ks) {
            bf8v a[4];
#pragma unroll
            for (int mt = 0; mt < 4; ++mt) {
                int rlog = ((mt >> 1) << 5) + ((lc >> 2) << 3) + ((mt & 1) << 2) + (lc & 3);
                int c8   = ((ks << 2) + quad + ((mt >> 1) << 2) + (lc >> 2)) & 7;  // swizzle
                a[mt] = *(const bf8v*)(&kss[buf][rlog][c8 * 8]);
            }
#pragma unroll
            for (int mt = 0; mt < 4; ++mt)
#pragma unroll
                for (int nt = 0; nt < 2; ++nt)
                    sc[mt][nt] = MFMA32(a[mt], bq[nt][ks], sc[mt][nt]);
        }

        // ---- P^T = exp(S^T + lrd) (q pre-scaled), packed into x32 B-frags
        bf8v pb[2][2];
#pragma unroll
        for (int mt = 0; mt < 4; ++mt) {
            f4v lrd = *(const f4v*)(rdl + cc * 64 + ((mt >> 1) << 5) + (quad << 3) + ((mt & 1) << 2));
#pragma unroll
            for (int nt = 0; nt < 2; ++nt)
#pragma unroll
                for (int i = 0; i < 4; ++i)
                    pb[mt >> 1][nt][(mt & 1) * 4 + i] =
                        (short)f2bf(__expf(sc[mt][nt][i] + lrd[i]));
        }

        // ---- PV: Out^T[d][r] += v^T[d][c2] @ P^T[c2][r], full-rate x32
#pragma unroll
        for (int kc = 0; kc < 2; ++kc)
#pragma unroll
            for (int dt = 0; dt < 8; ++dt) {
                bf8v a = *(const bf8v*)(&vs[buf][dt * 16 + lc][kc * 32 + quad * 8]);
#pragma unroll
                for (int nt = 0; nt < 2; ++nt)
                    acc[dt][nt] = MFMA32(a, pb[kc][nt], acc[dt][nt]);
            }

        // ---- write next chunk into the other buffer, single barrier ----
        if (cc < 31) {
            const int nbuf = buf ^ 1;
#pragma unroll
            for (int p = 0; p < 2; ++p) {
                int v = tid + p * 256;
                int c8 = ((v & 7) + (v >> 6)) & 7;
                *(u16x8*)(&kss[nbuf][v >> 3][c8 * 8]) = kreg[p];
            }
#pragma unroll
            for (int p = 0; p < 4; ++p) {
                int v = tid + p * 256;
                *(u16x8*)(&vs[nbuf][v >> 3][(v & 7) * 8]) = vreg[p];
            }
        }
        __syncthreads();
    }

    // epilogue: d = dt*16+quad*4+reg (4 consecutive), r = w*32+nt*16+lc
    float* ob = out + (size_t)(b * 2048 + g * 256 + jt * 128) * 1024 + h * 128;
#pragma unroll
    for (int dt = 0; dt < 8; ++dt)
#pragma unroll
        for (int nt = 0; nt < 2; ++nt) {
            int r = w * 32 + nt * 16 + lc;
            int d = dt * 16 + quad * 4;
            *(f4v*)(ob + (size_t)r * 1024 + d) = acc[dt][nt];
        }
}

// ---------------------------------------------------------------------------
extern "C" void kernel_launch(void* const* d_in, const int* in_sizes, int n_in,
                              void* d_out, int out_size, void* d_ws, size_t ws_size,
                              hipStream_t stream) {
    const float* x  = (const float*)d_in[0];   // [4][2048][1024]
    const float* Mq = (const float*)d_in[1];   // [1024][512]
    const float* Mk = (const float*)d_in[2];   // [1024][512]
    const float* Mv = (const float*)d_in[3];   // [1024][1024]
    float* out = (float*)d_out;                // [4][2048][1024]

    char* base = (char*)d_ws;
    unsigned short* xb  = (unsigned short*)base;  base += 16777216;  // x bf16
    unsigned short* wqt = (unsigned short*)base;  base += 1048576;   // Mq^T [512][1024]
    unsigned short* wkt = (unsigned short*)base;  base += 1048576;   // Mk^T (contig after wqt)
    unsigned short* wvt = (unsigned short*)base;  base += 2097152;   // Mv^T [1024][1024]
    unsigned short* pq  = (unsigned short*)base;  base += 8388608;   // [4*2048][512], pre-scaled /8
    unsigned short* pk  = (unsigned short*)base;  base += 8388608;
    unsigned short* pv  = (unsigned short*)base;  base += 16777216;  // [4*2048][1024]
    unsigned short* vt  = (unsigned short*)base;  base += 16777216;  // [32][128][2048]
    float* rdenl = (float*)base;                  base += 262144;    // [32][2048] = -ln colsum

    k_cvt<<<8192, 256, 0, stream>>>(x, xb, 2097152);
    k_cvtT3<<<dim3(16, 16, 2), 256, 0, stream>>>(Mq, Mk, Mv, wqt, wkt, wvt);
    k_gemm<<<dim3(64, 16), 256, 0, stream>>>(xb, wqt /* = Wt[2048][1024] */, pq, pk, pv);
    k_T<<<dim3(2, 32, 32), 256, 0, stream>>>(pv, vt);
    k_pass1<<<dim3(16, 32), 256, 0, stream>>>(pq, pk, rdenl);
    k_pass2<<<dim3(2, 8, 32), 256, 0, stream>>>(pq, pk, vt, rdenl, out);
}